// Round 17
// baseline (70.462 us; speedup 1.0000x reference)
//
#include <hip/hip_runtime.h>
#include <math.h>

#define IM 64
#define NBATCH 256
#define HID 64
#define TT 2048                 // table samples per program
#define PI_F 3.14159265358979f
#define MAGIC 0x5F3C2A11u

typedef _Float16 f16;
typedef _Float16 f16x8 __attribute__((ext_vector_type(8)));
typedef _Float16 f16x4 __attribute__((ext_vector_type(4)));
typedef _Float16 f16x2 __attribute__((ext_vector_type(2)));
typedef float    f32x4 __attribute__((ext_vector_type(4)));
typedef float    f32x2 __attribute__((ext_vector_type(2)));

// ws (f32 view):
//  [0,4096)    : tab[pg*TT + i] = o_pg(theta_i) + b3[pg]
//  [4096,4112) : u32 sentinels, one per producer block (value MAGIC)

static __device__ __forceinline__ f16x2 cvt2(float a, float b) {
    return __builtin_bit_cast(f16x2, __builtin_amdgcn_cvt_pkrtz(a, b));
}
static __device__ __forceinline__ f32x2 pmax2(f32x2 v) {
    return __builtin_elementwise_max(v, (f32x2)0.f);
}
static __device__ __forceinline__ f16x2 hmax2(f16x2 v) {
    return __builtin_elementwise_max(v, (f16x2)(_Float16)0.f);
}
// minimax atan2, max err ~2e-7 rad
static __device__ __forceinline__ float fast_atan2(float y, float x) {
    float ax = fabsf(x), ay = fabsf(y);
    float mx = fmaxf(ax, ay), mn = fminf(ax, ay);
    float t = mn * __builtin_amdgcn_rcpf(mx);
    float z = t * t;
    float p = fmaf(z, -0.01172120f, 0.05265332f);
    p = fmaf(z, p, -0.11643287f);
    p = fmaf(z, p,  0.19354346f);
    p = fmaf(z, p, -0.33262347f);
    p = fmaf(z, p,  0.99997726f);
    float r = t * p;
    r = (ay > ax)  ? 1.5707964f - r : r;
    r = (x < 0.f)  ? 3.1415927f - r : r;
    return (y < 0.f) ? -r : r;
}

// Single fused kernel, PLAIN launch (cooperative failed under graph capture,
// R16). 512 blocks x 256 thr, launch_bounds(256,2), LDS 18.5 KB => 2
// blocks/CU x 256 CU = all 512 co-resident => producer/consumer handshake
// cannot deadlock. Blocks 0..15 tabulate o_pg(theta) with the R15-proven
// LDS-staged MFMA chain (fast producer - R14's 73us was its SERIALIZED
// global gather, fixed by LDS staging), release-store sentinels at agent
// scope; all blocks acquire-wait then render a half-image. Sentinels
// persisting across replays are benign: producers always recompute
// identical values (deterministic inputs), so skipping the wait can only
// read identical data. First post-poison call waits properly.
__global__ __launch_bounds__(256, 2) void fused_kernel(
    const int*   __restrict__ program_id,
    const int*   __restrict__ shape_ids,
    const float* __restrict__ raw_positions,
    const float* __restrict__ w0, const float* __restrict__ b0,
    const float* __restrict__ w1, const float* __restrict__ b1,
    const float* __restrict__ w2, const float* __restrict__ b2,
    const float* __restrict__ w3, const float* __restrict__ b3,
    const float* __restrict__ lmr,
    float* __restrict__ wsf,
    float* __restrict__ out)
{
    __shared__ alignas(16) f16  W1[4096];   // [k][n], f16
    __shared__ alignas(16) f16  W2[4096];
    __shared__ alignas(16) f16  w0s[64], b0s[64];
    __shared__ alignas(16) float b1s[64], b2s[64], w3s[64];

    const int tid = threadIdx.x;
    const int blk = blockIdx.x;
    unsigned* sent = (unsigned*)(wsf + 4096);

    if (blk < 16) {
        // ---------------- producer: tabulate (R15-proven) ----------------
        const int pg = blk >> 3;
        {
            const f32x4* s1 = (const f32x4*)(w1 + pg*4096);
            const f32x4* s2 = (const f32x4*)(w2 + pg*4096);
            #pragma unroll
            for (int r = 0; r < 4; ++r) {
                const int i4 = r*256 + tid;               // [0,1024)
                const f32x4 v1 = s1[i4], v2 = s2[i4];
                ((f16x4*)W1)[i4] = (f16x4){(f16)v1[0], (f16)v1[1], (f16)v1[2], (f16)v1[3]};
                ((f16x4*)W2)[i4] = (f16x4){(f16)v2[0], (f16)v2[1], (f16)v2[2], (f16)v2[3]};
            }
            if (tid < 64) {
                w0s[tid] = (f16)w0[pg*64 + tid];
                b0s[tid] = (f16)b0[pg*64 + tid];
                b1s[tid] = b1[pg*64 + tid];
                b2s[tid] = b2[pg*64 + tid];
                w3s[tid] = w3[pg*64 + tid];
            }
        }
        __syncthreads();

        const int wave = tid >> 6;
        const int lane = tid & 63;
        const int u = lane & 15, g = lane >> 4;
        const int chunk = blk*4 + wave;           // [0,64)
        const int i0 = (chunk & 31)*64 + lane;    // sample index [0,TT)
        const float theta = -PI_F + (2.0f*PI_F/(float)(TT-1)) * (float)i0;

        // gather fragments from LDS (pipelined ds_reads)
        f16x8 wfA[4][2], wfB[4][2];
        #pragma unroll
        for (int mt = 0; mt < 4; ++mt)
            #pragma unroll
            for (int kh = 0; kh < 2; ++kh) {
                f16x8 a, bq;
                #pragma unroll
                for (int j = 0; j < 8; ++j) {
                    const int k1 = 32*kh + 8*g + j;                  // std order
                    const int k2 = 32*kh + 16*(j>>2) + 4*g + (j&3);  // L1-acc perm
                    a[j]  = W1[k1*64 + 16*mt + u];
                    bq[j] = W2[k2*64 + 16*mt + u];
                }
                wfA[mt][kh] = a; wfB[mt][kh] = bq;
            }
        f16x8 w0r[2], b0r[2];
        #pragma unroll
        for (int kh = 0; kh < 2; ++kh) {
            w0r[kh] = *(const f16x8*)&w0s[32*kh + 8*g];
            b0r[kh] = *(const f16x8*)&b0s[32*kh + 8*g];
        }
        f32x4 bv1[4], bv2[4], w3v[4];
        #pragma unroll
        for (int mt = 0; mt < 4; ++mt) {
            bv1[mt] = *(const f32x4*)&b1s[16*mt + 4*g];
            bv2[mt] = *(const f32x4*)&b2s[16*mt + 4*g];
            w3v[mt] = *(const f32x4*)&w3s[16*mt + 4*g];
        }

        float th[4];
        #pragma unroll
        for (int nt = 0; nt < 4; ++nt) th[nt] = __shfl(theta, 16*nt + u);

        // layer 0 -> B-fragments
        f16x8 bf[4][2];
        #pragma unroll
        for (int nt = 0; nt < 4; ++nt) {
            const f16 thh = (f16)th[nt];
            const f16x2 th2 = {thh, thh};
            #pragma unroll
            for (int kh = 0; kh < 2; ++kh) {
                union { f16x2 h2[4]; f16x8 v8; } uu;
                union { f16x8 v8; f16x2 h2[4]; } wv, bv_;
                wv.v8 = w0r[kh]; bv_.v8 = b0r[kh];
                #pragma unroll
                for (int q = 0; q < 4; ++q)
                    uu.h2[q] = hmax2(__builtin_elementwise_fma(th2, wv.h2[q], bv_.h2[q]));
                bf[nt][kh] = uu.v8;
            }
        }

        // layer 1 + in-lane repack
        f16x8 cf[4][2];
        #pragma unroll
        for (int mp = 0; mp < 2; ++mp) {
            f32x4 acc[2][4];
            #pragma unroll
            for (int mh = 0; mh < 2; ++mh) {
                const int mt = 2*mp + mh;
                #pragma unroll
                for (int nt = 0; nt < 4; ++nt) {
                    f32x4 a = __builtin_amdgcn_mfma_f32_16x16x32_f16(wfA[mt][0], bf[nt][0], bv1[mt], 0,0,0);
                    a = __builtin_amdgcn_mfma_f32_16x16x32_f16(wfA[mt][1], bf[nt][1], a, 0,0,0);
                    acc[mh][nt] = a;
                }
            }
            #pragma unroll
            for (int nt = 0; nt < 4; ++nt) {
                union { f16x2 h2[4]; f16x8 v8; } uu;
                #pragma unroll
                for (int hh = 0; hh < 2; ++hh) {
                    const f32x4 av = acc[hh][nt];
                    uu.h2[hh*2+0] = hmax2(cvt2(av[0], av[1]));
                    uu.h2[hh*2+1] = hmax2(cvt2(av[2], av[3]));
                }
                cf[nt][mp] = uu.v8;
            }
        }

        // layer 2 + head
        f32x2 hp2[4] = {{0.f,0.f},{0.f,0.f},{0.f,0.f},{0.f,0.f}};
        #pragma unroll
        for (int mt = 0; mt < 4; ++mt) {
            const f32x2 w301 = {w3v[mt][0], w3v[mt][1]}, w323 = {w3v[mt][2], w3v[mt][3]};
            #pragma unroll
            for (int nt = 0; nt < 4; ++nt) {
                f32x4 a = __builtin_amdgcn_mfma_f32_16x16x32_f16(wfB[mt][0], cf[nt][0], bv2[mt], 0,0,0);
                a = __builtin_amdgcn_mfma_f32_16x16x32_f16(wfB[mt][1], cf[nt][1], a, 0,0,0);
                f32x2 e01 = pmax2((f32x2){a[0], a[1]});
                f32x2 e23 = pmax2((f32x2){a[2], a[3]});
                hp2[nt] = e01*w301 + hp2[nt];
                hp2[nt] = e23*w323 + hp2[nt];
            }
        }
        float hp[4];
        #pragma unroll
        for (int nt = 0; nt < 4; ++nt) {
            hp[nt] = hp2[nt][0] + hp2[nt][1];
            hp[nt] += __shfl_xor(hp[nt], 16);
            hp[nt] += __shfl_xor(hp[nt], 32);
        }
        float ov = hp[0];
        if (g == 1) ov = hp[1];
        if (g == 2) ov = hp[2];
        if (g == 3) ov = hp[3];

        wsf[pg*TT + i0] = ov + b3[pg];

        __syncthreads();   // all waves' tab stores issued & drained (vmcnt)
        if (tid == 0)
            __hip_atomic_store(&sent[blk], MAGIC, __ATOMIC_RELEASE,
                               __HIP_MEMORY_SCOPE_AGENT);
    }

    // ---------------- wait for all 16 producers ----------------
    if (tid == 0) {
        int it = 0;
        for (;;) {
            unsigned ok = 1;
            #pragma unroll
            for (int i = 0; i < 16; ++i)
                ok &= (unsigned)(__hip_atomic_load(&sent[i], __ATOMIC_ACQUIRE,
                                                   __HIP_MEMORY_SCOPE_AGENT) == MAGIC);
            if (ok || ++it > (1 << 22)) break;   // cap: never hang the harness
            __builtin_amdgcn_s_sleep(8);
        }
    }
    __syncthreads();

    // ---------------- render: half-image per block, 8 px/thread ----------
    const int b    = blk >> 1;
    const int half = blk & 1;

    const int pid = program_id[b];
    const int pg0 = shape_ids[b*2 + 0];
    const int pg1 = shape_ids[b*2 + 1];
    const float posx0 = 1.f/(1.f + __expf(-raw_positions[b*4+0])) - 0.5f;
    const float posy0 = 1.f/(1.f + __expf(-raw_positions[b*4+1])) - 0.5f;
    const float posx1 = 1.f/(1.f + __expf(-raw_positions[b*4+2])) - 0.5f;
    const float posy1 = 1.f/(1.f + __expf(-raw_positions[b*4+3])) - 0.5f;
    const float mult0 = __expf(lmr[pg0]);
    const float mult1 = __expf(lmr[pg1]);
    const float* tb0 = wsf + pg0*TT;
    const float* tb1 = wsf + pg1*TT;

    #pragma unroll
    for (int q = 0; q < 2; ++q) {
        const int p4   = q*256 + tid;              // quad in half-image [0,512)
        const int px0  = half*2048 + p4*4;
        const int row  = px0 >> 6, col0 = px0 & 63;
        const float cy = -1.f + (2.f/63.f)*(float)row;

        f32x4 res;
        #pragma unroll
        for (int k = 0; k < 4; ++k) {
            const float cx = -1.f + (2.f/63.f)*(float)(col0 + k);
            float p01[2];
            #pragma unroll
            for (int s = 0; s < 2; ++s) {
                const float px = s ? posx1 : posx0;
                const float py = s ? posy1 : posy0;
                const float mu = s ? mult1 : mult0;
                const float* tb = s ? tb1 : tb0;
                const float dx = cx - px, dy = cy - py;
                const float theta = fast_atan2(dy, dx);
                const float r2 = sqrtf(dx*dx + dy*dy);
                float x = (theta + PI_F) * ((float)(TT-1)/(2.f*PI_F));
                x = fminf(fmaxf(x, 0.f), (float)(TT-1));
                const float fi = floorf(fminf(x, (float)(TT-2)));
                const int   i  = (int)fi;
                const float f  = x - fi;
                const float t0 = tb[i], t1 = tb[i+1];
                const float o  = fmaf(f, t1 - t0, t0);
                const float logit = mu * (__expf(o) - r2);
                p01[s] = __builtin_amdgcn_rcpf(1.f + __expf(-logit));
            }
            float r;
            if (pid == 0) {
                r = p01[0];
            } else {
                float c = (pid == 2) ? (p01[0] - p01[1]) : (p01[0] + p01[1]);
                r = fminf(fmaxf(c, 0.f), 1.f);
            }
            res[k] = r;
        }
        *(f32x4*)&out[b*(IM*IM) + px0] = res;
    }
}

extern "C" void kernel_launch(void* const* d_in, const int* in_sizes, int n_in,
                              void* d_out, int out_size, void* d_ws, size_t ws_size,
                              hipStream_t stream) {
    const int*   program_id    = (const int*)  d_in[0];
    const int*   shape_ids     = (const int*)  d_in[1];
    const float* raw_positions = (const float*)d_in[2];
    const float* w0            = (const float*)d_in[3];
    const float* b0            = (const float*)d_in[4];
    const float* w1            = (const float*)d_in[5];
    const float* b1            = (const float*)d_in[6];
    const float* w2            = (const float*)d_in[7];
    const float* b2            = (const float*)d_in[8];
    const float* w3            = (const float*)d_in[9];
    const float* b3            = (const float*)d_in[10];
    const float* lmr           = (const float*)d_in[11];
    float* out = (float*)d_out;
    float* wsf = (float*)d_ws;                // ~16.1 KB used

    fused_kernel<<<512, 256, 0, stream>>>(program_id, shape_ids, raw_positions,
                                          w0, b0, w1, b1, w2, b2, w3, b3, lmr,
                                          wsf, out);
}

// Round 18
// 15.916 us; speedup vs baseline: 4.4271x; 4.4271x over previous
//
#include <hip/hip_runtime.h>
#include <math.h>

#define IM 64
#define NBATCH 256
#define HID 64
#define TT 2048                 // table samples per program
#define PI_F 3.14159265358979f

typedef _Float16 f16;
typedef _Float16 f16x8 __attribute__((ext_vector_type(8)));
typedef _Float16 f16x4 __attribute__((ext_vector_type(4)));
typedef _Float16 f16x2 __attribute__((ext_vector_type(2)));
typedef float    f32x4 __attribute__((ext_vector_type(4)));
typedef float    f32x2 __attribute__((ext_vector_type(2)));

// ws (f32 view): [0, 4096) : tab[pg*TT + i] = o_pg(theta_i) + b3[pg]

static __device__ __forceinline__ f16x2 cvt2(float a, float b) {
    return __builtin_bit_cast(f16x2, __builtin_amdgcn_cvt_pkrtz(a, b));
}
static __device__ __forceinline__ f32x2 pmax2(f32x2 v) {
    return __builtin_elementwise_max(v, (f32x2)0.f);
}
static __device__ __forceinline__ f16x2 hmax2(f16x2 v) {
    return __builtin_elementwise_max(v, (f16x2)(_Float16)0.f);
}
// minimax atan2, max err ~2e-7 rad
static __device__ __forceinline__ float fast_atan2(float y, float x) {
    float ax = fabsf(x), ay = fabsf(y);
    float mx = fmaxf(ax, ay), mn = fminf(ax, ay);
    float t = mn * __builtin_amdgcn_rcpf(mx);
    float z = t * t;
    float p = fmaf(z, -0.01172120f, 0.05265332f);
    p = fmaf(z, p, -0.11643287f);
    p = fmaf(z, p,  0.19354346f);
    p = fmaf(z, p, -0.33262347f);
    p = fmaf(z, p,  0.99997726f);
    float r = t * p;
    r = (ay > ax)  ? 1.5707964f - r : r;
    r = (x < 0.f)  ? 3.1415927f - r : r;
    return (y < 0.f) ? -r : r;
}

// Setup: 16 blocks x 256 thr (R15-proven). Block blk (pg = blk>>3) stages
// its program's weights into LDS via coalesced float4 loads, then each wave
// tabulates 64 samples of o_pg(theta) through the MFMA chain.
__global__ __launch_bounds__(256) void setup_kernel(
    const float* __restrict__ w0, const float* __restrict__ b0,
    const float* __restrict__ w1, const float* __restrict__ b1,
    const float* __restrict__ w2, const float* __restrict__ b2,
    const float* __restrict__ w3, const float* __restrict__ b3,
    float* __restrict__ wsf)
{
    __shared__ alignas(16) f16  W1[4096];   // [k][n], f16
    __shared__ alignas(16) f16  W2[4096];
    __shared__ alignas(16) f16  w0s[64], b0s[64];
    __shared__ alignas(16) float b1s[64], b2s[64], w3s[64];

    const int tid = threadIdx.x;
    const int blk = blockIdx.x;
    const int pg  = blk >> 3;

    {
        const f32x4* s1 = (const f32x4*)(w1 + pg*4096);
        const f32x4* s2 = (const f32x4*)(w2 + pg*4096);
        #pragma unroll
        for (int r = 0; r < 4; ++r) {
            const int i4 = r*256 + tid;               // [0,1024)
            const f32x4 v1 = s1[i4], v2 = s2[i4];
            ((f16x4*)W1)[i4] = (f16x4){(f16)v1[0], (f16)v1[1], (f16)v1[2], (f16)v1[3]};
            ((f16x4*)W2)[i4] = (f16x4){(f16)v2[0], (f16)v2[1], (f16)v2[2], (f16)v2[3]};
        }
        if (tid < 64) {
            w0s[tid] = (f16)w0[pg*64 + tid];
            b0s[tid] = (f16)b0[pg*64 + tid];
            b1s[tid] = b1[pg*64 + tid];
            b2s[tid] = b2[pg*64 + tid];
            w3s[tid] = w3[pg*64 + tid];
        }
    }
    __syncthreads();

    const int wave = tid >> 6;
    const int lane = tid & 63;
    const int u = lane & 15, g = lane >> 4;
    const int chunk = blk*4 + wave;           // [0,64)
    const int i0 = (chunk & 31)*64 + lane;    // sample index [0,TT)
    const float theta = -PI_F + (2.0f*PI_F/(float)(TT-1)) * (float)i0;

    f16x8 wfA[4][2], wfB[4][2];
    #pragma unroll
    for (int mt = 0; mt < 4; ++mt)
        #pragma unroll
        for (int kh = 0; kh < 2; ++kh) {
            f16x8 a, bq;
            #pragma unroll
            for (int j = 0; j < 8; ++j) {
                const int k1 = 32*kh + 8*g + j;                  // std order
                const int k2 = 32*kh + 16*(j>>2) + 4*g + (j&3);  // L1-acc perm
                a[j]  = W1[k1*64 + 16*mt + u];
                bq[j] = W2[k2*64 + 16*mt + u];
            }
            wfA[mt][kh] = a; wfB[mt][kh] = bq;
        }
    f16x8 w0r[2], b0r[2];
    #pragma unroll
    for (int kh = 0; kh < 2; ++kh) {
        w0r[kh] = *(const f16x8*)&w0s[32*kh + 8*g];
        b0r[kh] = *(const f16x8*)&b0s[32*kh + 8*g];
    }
    f32x4 bv1[4], bv2[4], w3v[4];
    #pragma unroll
    for (int mt = 0; mt < 4; ++mt) {
        bv1[mt] = *(const f32x4*)&b1s[16*mt + 4*g];
        bv2[mt] = *(const f32x4*)&b2s[16*mt + 4*g];
        w3v[mt] = *(const f32x4*)&w3s[16*mt + 4*g];
    }

    float th[4];
    #pragma unroll
    for (int nt = 0; nt < 4; ++nt) th[nt] = __shfl(theta, 16*nt + u);

    f16x8 bf[4][2];
    #pragma unroll
    for (int nt = 0; nt < 4; ++nt) {
        const f16 thh = (f16)th[nt];
        const f16x2 th2 = {thh, thh};
        #pragma unroll
        for (int kh = 0; kh < 2; ++kh) {
            union { f16x2 h2[4]; f16x8 v8; } uu;
            union { f16x8 v8; f16x2 h2[4]; } wv, bv_;
            wv.v8 = w0r[kh]; bv_.v8 = b0r[kh];
            #pragma unroll
            for (int q = 0; q < 4; ++q)
                uu.h2[q] = hmax2(__builtin_elementwise_fma(th2, wv.h2[q], bv_.h2[q]));
            bf[nt][kh] = uu.v8;
        }
    }

    f16x8 cf[4][2];
    #pragma unroll
    for (int mp = 0; mp < 2; ++mp) {
        f32x4 acc[2][4];
        #pragma unroll
        for (int mh = 0; mh < 2; ++mh) {
            const int mt = 2*mp + mh;
            #pragma unroll
            for (int nt = 0; nt < 4; ++nt) {
                f32x4 a = __builtin_amdgcn_mfma_f32_16x16x32_f16(wfA[mt][0], bf[nt][0], bv1[mt], 0,0,0);
                a = __builtin_amdgcn_mfma_f32_16x16x32_f16(wfA[mt][1], bf[nt][1], a, 0,0,0);
                acc[mh][nt] = a;
            }
        }
        #pragma unroll
        for (int nt = 0; nt < 4; ++nt) {
            union { f16x2 h2[4]; f16x8 v8; } uu;
            #pragma unroll
            for (int hh = 0; hh < 2; ++hh) {
                const f32x4 av = acc[hh][nt];
                uu.h2[hh*2+0] = hmax2(cvt2(av[0], av[1]));
                uu.h2[hh*2+1] = hmax2(cvt2(av[2], av[3]));
            }
            cf[nt][mp] = uu.v8;
        }
    }

    f32x2 hp2[4] = {{0.f,0.f},{0.f,0.f},{0.f,0.f},{0.f,0.f}};
    #pragma unroll
    for (int mt = 0; mt < 4; ++mt) {
        const f32x2 w301 = {w3v[mt][0], w3v[mt][1]}, w323 = {w3v[mt][2], w3v[mt][3]};
        #pragma unroll
        for (int nt = 0; nt < 4; ++nt) {
            f32x4 a = __builtin_amdgcn_mfma_f32_16x16x32_f16(wfB[mt][0], cf[nt][0], bv2[mt], 0,0,0);
            a = __builtin_amdgcn_mfma_f32_16x16x32_f16(wfB[mt][1], cf[nt][1], a, 0,0,0);
            f32x2 e01 = pmax2((f32x2){a[0], a[1]});
            f32x2 e23 = pmax2((f32x2){a[2], a[3]});
            hp2[nt] = e01*w301 + hp2[nt];
            hp2[nt] = e23*w323 + hp2[nt];
        }
    }
    float hp[4];
    #pragma unroll
    for (int nt = 0; nt < 4; ++nt) {
        hp[nt] = hp2[nt][0] + hp2[nt][1];
        hp[nt] += __shfl_xor(hp[nt], 16);
        hp[nt] += __shfl_xor(hp[nt], 32);
    }
    float ov = hp[0];
    if (g == 1) ov = hp[1];
    if (g == 2) ov = hp[2];
    if (g == 3) ov = hp[3];

    wsf[pg*TT + i0] = ov + b3[pg];
}

// One shape's probability at a pixel (table lerp path).
static __device__ __forceinline__ float px_prob(
    const float* __restrict__ tb, float mu, float dx, float dy)
{
    const float theta = fast_atan2(dy, dx);
    const float r2 = sqrtf(dx*dx + dy*dy);
    float x = fmaf(theta, (float)(TT-1)/(2.f*PI_F), (float)(TT-1)*0.5f);
    x = fminf(fmaxf(x, 0.f), (float)(TT-1));
    const float fi = floorf(fminf(x, (float)(TT-2)));
    const int   i  = (int)fi;
    const float f  = x - fi;
    const float t0 = tb[i], t1 = tb[i+1];
    const float o  = fmaf(f, t1 - t0, t0);
    const float logit = mu * (__expf(o) - r2);
    return __builtin_amdgcn_rcpf(1.f + __expf(-logit));
}

// Render: 1024 blocks x 256 thr; block = quarter-image of batch b.
// pid==0 blocks skip shape 1 entirely (uniform branch, ~1/3 of blocks).
__global__ __launch_bounds__(256) void render_kernel(
    const int*   __restrict__ program_id,
    const int*   __restrict__ shape_ids,
    const float* __restrict__ raw_positions,
    const float* __restrict__ lmr,
    const float* __restrict__ wsf,
    float* __restrict__ out)
{
    const int blk = blockIdx.x;
    const int b   = blk >> 2;
    const int q4  = blk & 3;
    const int tid = threadIdx.x;

    const int pid = program_id[b];
    const int pg0 = shape_ids[b*2 + 0];
    const float posx0 = 1.f/(1.f + __expf(-raw_positions[b*4+0])) - 0.5f;
    const float posy0 = 1.f/(1.f + __expf(-raw_positions[b*4+1])) - 0.5f;
    const float mult0 = __expf(lmr[pg0]);
    const float* tb0 = wsf + pg0*TT;

    const int px0  = q4*1024 + tid*4;
    const int row  = px0 >> 6, col0 = px0 & 63;
    const float cy = -1.f + (2.f/63.f)*(float)row;

    f32x4 res;
    if (pid == 0) {
        #pragma unroll
        for (int k = 0; k < 4; ++k) {
            const float cx = -1.f + (2.f/63.f)*(float)(col0 + k);
            res[k] = px_prob(tb0, mult0, cx - posx0, cy - posy0);
        }
    } else {
        const int pg1 = shape_ids[b*2 + 1];
        const float posx1 = 1.f/(1.f + __expf(-raw_positions[b*4+2])) - 0.5f;
        const float posy1 = 1.f/(1.f + __expf(-raw_positions[b*4+3])) - 0.5f;
        const float mult1 = __expf(lmr[pg1]);
        const float* tb1 = wsf + pg1*TT;
        const bool sub = (pid == 2);
        #pragma unroll
        for (int k = 0; k < 4; ++k) {
            const float cx = -1.f + (2.f/63.f)*(float)(col0 + k);
            const float p0 = px_prob(tb0, mult0, cx - posx0, cy - posy0);
            const float p1 = px_prob(tb1, mult1, cx - posx1, cy - posy1);
            const float c  = sub ? (p0 - p1) : (p0 + p1);
            res[k] = fminf(fmaxf(c, 0.f), 1.f);
        }
    }
    *(f32x4*)&out[b*(IM*IM) + px0] = res;
}

extern "C" void kernel_launch(void* const* d_in, const int* in_sizes, int n_in,
                              void* d_out, int out_size, void* d_ws, size_t ws_size,
                              hipStream_t stream) {
    const int*   program_id    = (const int*)  d_in[0];
    const int*   shape_ids     = (const int*)  d_in[1];
    const float* raw_positions = (const float*)d_in[2];
    const float* w0            = (const float*)d_in[3];
    const float* b0            = (const float*)d_in[4];
    const float* w1            = (const float*)d_in[5];
    const float* b1            = (const float*)d_in[6];
    const float* w2            = (const float*)d_in[7];
    const float* b2            = (const float*)d_in[8];
    const float* w3            = (const float*)d_in[9];
    const float* b3            = (const float*)d_in[10];
    const float* lmr           = (const float*)d_in[11];
    float* out = (float*)d_out;
    float* wsf = (float*)d_ws;                // 16 KB used (tab only)

    setup_kernel<<<16, 256, 0, stream>>>(w0, b0, w1, b1, w2, b2, w3, b3, wsf);

    render_kernel<<<1024, 256, 0, stream>>>(program_id, shape_ids,
                                            raw_positions, lmr, wsf, out);
}